// Round 2
// baseline (784.928 us; speedup 1.0000x reference)
//
#include <hip/hip_runtime.h>

typedef unsigned short u16;
typedef __attribute__((ext_vector_type(8))) short bf16x8;
typedef __attribute__((ext_vector_type(4))) float fx4;

#define MFMA16(a, b, c) __builtin_amdgcn_mfma_f32_16x16x32_bf16((a), (b), (c), 0, 0, 0)

__device__ __forceinline__ u16 f2bf(float f) {
  unsigned u = __float_as_uint(f);
  u += 0x7fffu + ((u >> 16) & 1u);
  return (u16)(u >> 16);
}

__device__ __forceinline__ void gload_lds16(const void* g, void* l) {
  __builtin_amdgcn_global_load_lds((const __attribute__((address_space(1))) void*)g,
                                   (__attribute__((address_space(3))) void*)l,
                                   16, 0, 0);
}

// ---------------- transpose + fp32->bf16 convert: dst[c][r] = src[r][c] ----------------
__global__ __launch_bounds__(256) void tcvt(const float* __restrict__ src,
                                            u16* __restrict__ dst, int R, int C) {
  __shared__ float t[32][33];
  const int tx = threadIdx.x & 31, ty = threadIdx.x >> 5;  // 32x8
  const int bx = blockIdx.x, by = blockIdx.y;
#pragma unroll
  for (int i = 0; i < 4; ++i)
    t[ty + i * 8][tx] = src[(size_t)(by * 32 + ty + i * 8) * C + bx * 32 + tx];
  __syncthreads();
#pragma unroll
  for (int i = 0; i < 4; ++i)
    dst[(size_t)(bx * 32 + ty + i * 8) * R + by * 32 + tx] = f2bf(t[tx][ty + i * 8]);
}

// ---------------- layernorm: fp32 [rows][1024] -> bf16 ----------------
__global__ __launch_bounds__(256) void ln_kernel(const float* __restrict__ x,
                                                 const float* __restrict__ sc,
                                                 const float* __restrict__ sh,
                                                 u16* __restrict__ out) {
  const int row = blockIdx.x, tid = threadIdx.x;
  const float4 v = ((const float4*)(x + (size_t)row * 1024))[tid];
  float s = v.x + v.y + v.z + v.w;
  float ss = v.x * v.x + v.y * v.y + v.z * v.z + v.w * v.w;
#pragma unroll
  for (int d = 32; d >= 1; d >>= 1) {
    s += __shfl_xor(s, d);
    ss += __shfl_xor(ss, d);
  }
  __shared__ float rs[4], rq[4];
  const int w = tid >> 6;
  if ((tid & 63) == 0) { rs[w] = s; rq[w] = ss; }
  __syncthreads();
  s = rs[0] + rs[1] + rs[2] + rs[3];
  ss = rq[0] + rq[1] + rq[2] + rq[3];
  const float mean = s * (1.f / 1024.f);
  const float var = ss * (1.f / 1024.f) - mean * mean;
  const float rstd = rsqrtf(var + 1e-5f);
  const float4 g = ((const float4*)sc)[tid];
  const float4 b = ((const float4*)sh)[tid];
  ushort4 o;
  o.x = f2bf(g.x * (v.x - mean) * rstd + b.x);
  o.y = f2bf(g.y * (v.y - mean) * rstd + b.y);
  o.z = f2bf(g.z * (v.z - mean) * rstd + b.z);
  o.w = f2bf(g.w * (v.w - mean) * rstd + b.w);
  ((ushort4*)(out + (size_t)row * 1024))[tid] = o;
}

// ---------------- 128x128 bf16 GEMM, C = A[M,K] @ Bt[N,K]^T, fp32 accum ----------------
// MODE 0: QKV scatter  (q [bh][S][64], k [bh][S][64], vT [bh][64][S])
// MODE 1: d_out = X + acc            (fp32)
// MODE 2: g = bf16(gelu(acc + b1))
// MODE 3: d_out = d_out + acc + b2   (fp32, in-place; same-thread RMW)
template <int MODE>
__global__ __launch_bounds__(256) void gemm_bf16(
    const u16* __restrict__ A, const u16* __restrict__ Bt, int M, int N, int K,
    void* __restrict__ outp, const float* __restrict__ aux,
    u16* __restrict__ qd, u16* __restrict__ kd, u16* __restrict__ vd) {
  __shared__ u16 lA[128 * 32];
  __shared__ u16 lB[128 * 32];
  const int tid = threadIdx.x;
  const int w = tid >> 6, lane = tid & 63;
  const int lo = lane & 15, hi = lane >> 4;
  const int tM = blockIdx.y * 128, tN = blockIdx.x * 128;
  const int wr = (w >> 1) << 6, wc = (w & 1) << 6;

  const u16 *sA[2], *sB[2];
  u16 *dA[2], *dB[2];
#pragma unroll
  for (int p = 0; p < 2; ++p) {
    const int c = p * 256 + tid;
    const int r = c >> 2, gs = (c & 3) ^ (r & 3);   // source-side XOR swizzle
    sA[p] = A + (size_t)(tM + r) * K + gs * 8;
    sB[p] = Bt + (size_t)(tN + r) * K + gs * 8;
    dA[p] = &lA[(p * 256 + w * 64) * 8];
    dB[p] = &lB[(p * 256 + w * 64) * 8];
  }

  fx4 acc[4][4];
#pragma unroll
  for (int m = 0; m < 4; ++m)
#pragma unroll
    for (int n = 0; n < 4; ++n) acc[m][n] = (fx4){0.f, 0.f, 0.f, 0.f};

  for (int kk = 0; kk < K; kk += 32) {
    __syncthreads();
#pragma unroll
    for (int p = 0; p < 2; ++p) {
      gload_lds16(sA[p] + kk, dA[p]);
      gload_lds16(sB[p] + kk, dB[p]);
    }
    __syncthreads();
    bf16x8 af[4], bfr[4];
#pragma unroll
    for (int m = 0; m < 4; ++m) {
      const int r = wr + m * 16 + lo;
      af[m] = *(const bf16x8*)&lA[r * 32 + ((hi ^ (r & 3)) << 3)];
    }
#pragma unroll
    for (int n = 0; n < 4; ++n) {
      const int r = wc + n * 16 + lo;
      bfr[n] = *(const bf16x8*)&lB[r * 32 + ((hi ^ (r & 3)) << 3)];
    }
#pragma unroll
    for (int m = 0; m < 4; ++m)
#pragma unroll
      for (int n = 0; n < 4; ++n) acc[m][n] = MFMA16(af[m], bfr[n], acc[m][n]);
  }

#pragma unroll
  for (int m = 0; m < 4; ++m) {
    const int rgb = tM + wr + m * 16 + hi * 4;
#pragma unroll
    for (int n = 0; n < 4; ++n) {
      const int cg = tN + wc + n * 16 + lo;
#pragma unroll
      for (int r = 0; r < 4; ++r) {
        const float v = acc[m][n][r];
        const int rg = rgb + r;
        if constexpr (MODE == 0) {
          const int which = cg >> 10, c = cg & 1023;
          const int head = c >> 6, dhi = c & 63;
          const int b = rg >> 11, sidx = rg & 2047;
          const int bh = b * 16 + head;
          const u16 bv = f2bf(v);
          if (which == 0)      qd[((size_t)bh * 2048 + sidx) * 64 + dhi] = bv;
          else if (which == 1) kd[((size_t)bh * 2048 + sidx) * 64 + dhi] = bv;
          else                 vd[((size_t)bh * 64 + dhi) * 2048 + sidx] = bv;
        } else if constexpr (MODE == 1) {
          float* o = (float*)outp;
          const size_t idx = (size_t)rg * 1024 + cg;
          o[idx] = aux[idx] + v;
        } else if constexpr (MODE == 2) {
          const float xx = v + aux[cg];
          const float t = xx + 0.044715f * xx * xx * xx;
          const float e = __expf(1.5957691216057308f * t);  // 2*sqrt(2/pi)
          const float th = 1.f - 2.f / (e + 1.f);
          ((u16*)outp)[(size_t)rg * 4096 + cg] = f2bf(0.5f * xx * (1.f + th));
        } else {
          float* o = (float*)outp;
          const size_t idx = (size_t)rg * 1024 + cg;
          o[idx] = o[idx] + v + aux[cg];
        }
      }
    }
  }
}

// ---------------- causal flash attention, bf16 MFMA ----------------
// grid: (S/128, BH). 4 waves/block, each wave owns 32 q rows. dh = 64.
__global__ __launch_bounds__(256) void attn_kernel(const u16* __restrict__ Q,
                                                   const u16* __restrict__ Kg,
                                                   const u16* __restrict__ Vt,
                                                   u16* __restrict__ ctx) {
  __shared__ u16 Plds[4][2048];
  const int tid = threadIdx.x;
  const int w = tid >> 6, lane = tid & 63;
  const int lo = lane & 15, hi = lane >> 4;
  const int bh = blockIdx.y;
  const int qb = blockIdx.x * 128 + w * 32;
  const u16* Qb = Q + (size_t)bh * 2048 * 64;
  const u16* Kb = Kg + (size_t)bh * 2048 * 64;
  const u16* Vb = Vt + (size_t)bh * 64 * 2048;
  u16* Pw = Plds[w];

  bf16x8 qf[2][2];
#pragma unroll
  for (int rt = 0; rt < 2; ++rt)
#pragma unroll
    for (int kc = 0; kc < 2; ++kc)
      qf[rt][kc] = *(const bf16x8*)&Qb[(size_t)(qb + rt * 16 + lo) * 64 + kc * 32 + hi * 8];

  fx4 accO[2][4];
  float mrow[2][4], lrow[2][4];
#pragma unroll
  for (int rt = 0; rt < 2; ++rt)
#pragma unroll
    for (int t = 0; t < 4; ++t) {
      accO[rt][t] = (fx4){0.f, 0.f, 0.f, 0.f};
      mrow[rt][t] = -1e30f;
      lrow[rt][t] = 0.f;
    }

  for (int kb = 0; kb <= qb + 31; kb += 64) {
    fx4 s[2][4];
#pragma unroll
    for (int t = 0; t < 4; ++t) {
      const u16* Kt = Kb + (size_t)(kb + t * 16 + lo) * 64;
      const bf16x8 kf0 = *(const bf16x8*)&Kt[hi * 8];
      const bf16x8 kf1 = *(const bf16x8*)&Kt[32 + hi * 8];
#pragma unroll
      for (int rt = 0; rt < 2; ++rt) {
        fx4 z = (fx4){0.f, 0.f, 0.f, 0.f};
        z = MFMA16(qf[rt][0], kf0, z);
        z = MFMA16(qf[rt][1], kf1, z);
        s[rt][t] = z;
      }
    }
#pragma unroll
    for (int rt = 0; rt < 2; ++rt) {
#pragma unroll
      for (int t = 0; t < 4; ++t)
#pragma unroll
        for (int r = 0; r < 4; ++r) {
          const int key = kb + t * 16 + lo;
          const int qr = qb + rt * 16 + hi * 4 + r;
          const float sv = s[rt][t][r] * 0.125f;
          s[rt][t][r] = (key > qr) ? -1e30f : sv;
        }
      float mt[4];
#pragma unroll
      for (int r = 0; r < 4; ++r)
        mt[r] = fmaxf(fmaxf(s[rt][0][r], s[rt][1][r]), fmaxf(s[rt][2][r], s[rt][3][r]));
#pragma unroll
      for (int d = 8; d >= 1; d >>= 1)
#pragma unroll
        for (int r = 0; r < 4; ++r) mt[r] = fmaxf(mt[r], __shfl_xor(mt[r], d));
      float fsc[4], la[4];
#pragma unroll
      for (int r = 0; r < 4; ++r) {
        const float mn = fmaxf(mrow[rt][r], mt[r]);
        fsc[r] = __expf(mrow[rt][r] - mn);
        mrow[rt][r] = mn;
        la[r] = 0.f;
      }
#pragma unroll
      for (int t = 0; t < 4; ++t)
#pragma unroll
        for (int r = 0; r < 4; ++r) {
          const float p = __expf(s[rt][t][r] - mrow[rt][r]);
          s[rt][t][r] = p;
          la[r] += p;
        }
#pragma unroll
      for (int d = 8; d >= 1; d >>= 1)
#pragma unroll
        for (int r = 0; r < 4; ++r) la[r] += __shfl_xor(la[r], d);
#pragma unroll
      for (int r = 0; r < 4; ++r) lrow[rt][r] = lrow[rt][r] * fsc[r] + la[r];
#pragma unroll
      for (int t2 = 0; t2 < 4; ++t2)
#pragma unroll
        for (int r = 0; r < 4; ++r) accO[rt][t2][r] *= fsc[r];
      // P -> LDS (XOR-swizzled to avoid 16-way conflicts on the b128 re-read)
#pragma unroll
      for (int t = 0; t < 4; ++t)
#pragma unroll
        for (int r = 0; r < 4; ++r) {
          const int row = rt * 16 + hi * 4 + r;
          const int colB = (t * 16 + lo) * 2;
          Pw[(row * 128 + (colB ^ ((row & 7) << 4))) >> 1] = f2bf(s[rt][t][r]);
        }
    }
    asm volatile("s_waitcnt lgkmcnt(0)" ::: "memory");
    bf16x8 pf[2][2];
#pragma unroll
    for (int rt = 0; rt < 2; ++rt)
#pragma unroll
      for (int kc = 0; kc < 2; ++kc) {
        const int row = rt * 16 + lo;
        const int colB = kc * 64 + hi * 16;
        pf[rt][kc] = *(const bf16x8*)((const char*)Pw + row * 128 + (colB ^ ((row & 7) << 4)));
      }
#pragma unroll
    for (int t2 = 0; t2 < 4; ++t2) {
      const u16* Vtt = Vb + (size_t)(t2 * 16 + lo) * 2048 + kb;
      const bf16x8 vf0 = *(const bf16x8*)&Vtt[hi * 8];
      const bf16x8 vf1 = *(const bf16x8*)&Vtt[32 + hi * 8];
#pragma unroll
      for (int rt = 0; rt < 2; ++rt) {
        accO[rt][t2] = MFMA16(pf[rt][0], vf0, accO[rt][t2]);
        accO[rt][t2] = MFMA16(pf[rt][1], vf1, accO[rt][t2]);
      }
    }
  }
  const int b = bh >> 4, h = bh & 15;
#pragma unroll
  for (int rt = 0; rt < 2; ++rt)
#pragma unroll
    for (int t2 = 0; t2 < 4; ++t2)
#pragma unroll
      for (int r = 0; r < 4; ++r) {
        const int rg = b * 2048 + qb + rt * 16 + hi * 4 + r;
        const int cg = h * 64 + t2 * 16 + lo;
        ctx[(size_t)rg * 1024 + cg] = f2bf(accO[rt][t2][r] / lrow[rt][r]);
      }
}

// ---------------- host ----------------
extern "C" void kernel_launch(void* const* d_in, const int* in_sizes, int n_in,
                              void* d_out, int out_size, void* d_ws, size_t ws_size,
                              hipStream_t stream) {
  const float* X    = (const float*)d_in[0];
  const float* Wq   = (const float*)d_in[1];
  const float* Wk   = (const float*)d_in[2];
  const float* Wv   = (const float*)d_in[3];
  const float* Wo   = (const float*)d_in[4];
  const float* W1   = (const float*)d_in[5];
  const float* b1   = (const float*)d_in[6];
  const float* W2   = (const float*)d_in[7];
  const float* b2   = (const float*)d_in[8];
  const float* ln1s = (const float*)d_in[9];
  const float* ln1b = (const float*)d_in[10];
  const float* ln2s = (const float*)d_in[11];
  const float* ln2b = (const float*)d_in[12];

  const size_t SZ_WQKVT = 3072UL * 1024;
  const size_t SZ_WOT   = 1024UL * 1024;
  const size_t SZ_W1T   = 4096UL * 1024;
  const size_t SZ_W2T   = 1024UL * 4096;
  const size_t SZ_H     = 8192UL * 1024;
  const size_t SZ_QKV   = 64UL * 2048 * 64;

  u16* WqkvT = (u16*)d_ws;
  u16* WoT   = WqkvT + SZ_WQKVT;
  u16* W1T   = WoT + SZ_WOT;
  u16* W2T   = W1T + SZ_W1T;
  u16* hbuf  = W2T + SZ_W2T;
  u16* qbuf  = hbuf + SZ_H;
  u16* kbuf  = qbuf + SZ_QKV;
  u16* vbuf  = kbuf + SZ_QKV;
  u16* gbuf  = vbuf + SZ_QKV;
  u16* ctx   = hbuf;  // reuse (h dead after QKV GEMM)
  u16* h2    = qbuf;  // reuse (q/k dead after attention)

  float* out = (float*)d_out;
  dim3 blk(256);

  // weights -> bf16 transposed
  tcvt<<<dim3(32, 32), blk, 0, stream>>>(Wq, WqkvT, 1024, 1024);
  tcvt<<<dim3(32, 32), blk, 0, stream>>>(Wk, WqkvT + 1024 * 1024, 1024, 1024);
  tcvt<<<dim3(32, 32), blk, 0, stream>>>(Wv, WqkvT + 2 * 1024 * 1024, 1024, 1024);
  tcvt<<<dim3(32, 32), blk, 0, stream>>>(Wo, WoT, 1024, 1024);
  tcvt<<<dim3(128, 32), blk, 0, stream>>>(W1, W1T, 1024, 4096);
  tcvt<<<dim3(32, 128), blk, 0, stream>>>(W2, W2T, 4096, 1024);

  // LN1
  ln_kernel<<<8192, blk, 0, stream>>>(X, ln1s, ln1b, hbuf);
  // QKV
  gemm_bf16<0><<<dim3(24, 64), blk, 0, stream>>>(hbuf, WqkvT, 8192, 3072, 1024,
                                                 nullptr, nullptr, qbuf, kbuf, vbuf);
  // attention
  attn_kernel<<<dim3(16, 64), blk, 0, stream>>>(qbuf, kbuf, vbuf, ctx);
  // Wo + residual -> d_out (X1)
  gemm_bf16<1><<<dim3(8, 64), blk, 0, stream>>>(ctx, WoT, 8192, 1024, 1024,
                                                out, X, nullptr, nullptr, nullptr);
  // LN2
  ln_kernel<<<8192, blk, 0, stream>>>(out, ln2s, ln2b, h2);
  // MLP1: gelu(h2@W1 + b1)
  gemm_bf16<2><<<dim3(32, 64), blk, 0, stream>>>(h2, W1T, 8192, 4096, 1024,
                                                 gbuf, b1, nullptr, nullptr, nullptr);
  // MLP2: d_out = X1 + g@W2 + b2
  gemm_bf16<3><<<dim3(8, 64), blk, 0, stream>>>(gbuf, W2T, 8192, 1024, 4096,
                                                out, b2, nullptr, nullptr, nullptr);
}

// Round 4
// 519.235 us; speedup vs baseline: 1.5117x; 1.5117x over previous
//
#include <hip/hip_runtime.h>

typedef unsigned short u16;
typedef __attribute__((ext_vector_type(8))) short bf16x8;
typedef __attribute__((ext_vector_type(4))) float fx4;

#define MFMA16(a, b, c) __builtin_amdgcn_mfma_f32_16x16x32_bf16((a), (b), (c), 0, 0, 0)

__device__ __forceinline__ u16 f2bf(float f) {
  unsigned u = __float_as_uint(f);
  u += 0x7fffu + ((u >> 16) & 1u);
  return (u16)(u >> 16);
}

__device__ __forceinline__ void gload_lds16(const void* g, void* l) {
  __builtin_amdgcn_global_load_lds((const __attribute__((address_space(1))) void*)g,
                                   (__attribute__((address_space(3))) void*)l,
                                   16, 0, 0);
}

// ---------------- transpose + fp32->bf16 convert: dst[c][r] = src[r][c] ----------------
__global__ __launch_bounds__(256) void tcvt(const float* __restrict__ src,
                                            u16* __restrict__ dst, int R, int C) {
  __shared__ float t[32][33];
  const int tx = threadIdx.x & 31, ty = threadIdx.x >> 5;  // 32x8
  const int bx = blockIdx.x, by = blockIdx.y;
#pragma unroll
  for (int i = 0; i < 4; ++i)
    t[ty + i * 8][tx] = src[(size_t)(by * 32 + ty + i * 8) * C + bx * 32 + tx];
  __syncthreads();
#pragma unroll
  for (int i = 0; i < 4; ++i)
    dst[(size_t)(bx * 32 + ty + i * 8) * R + by * 32 + tx] = f2bf(t[tx][ty + i * 8]);
}

// ---------------- layernorm: fp32 [rows][1024] -> bf16 ----------------
__global__ __launch_bounds__(256) void ln_kernel(const float* __restrict__ x,
                                                 const float* __restrict__ sc,
                                                 const float* __restrict__ sh,
                                                 u16* __restrict__ out) {
  const int row = blockIdx.x, tid = threadIdx.x;
  const float4 v = ((const float4*)(x + (size_t)row * 1024))[tid];
  float s = v.x + v.y + v.z + v.w;
  float ss = v.x * v.x + v.y * v.y + v.z * v.z + v.w * v.w;
#pragma unroll
  for (int d = 32; d >= 1; d >>= 1) {
    s += __shfl_xor(s, d);
    ss += __shfl_xor(ss, d);
  }
  __shared__ float rs[4], rq[4];
  const int w = tid >> 6;
  if ((tid & 63) == 0) { rs[w] = s; rq[w] = ss; }
  __syncthreads();
  s = rs[0] + rs[1] + rs[2] + rs[3];
  ss = rq[0] + rq[1] + rq[2] + rq[3];
  const float mean = s * (1.f / 1024.f);
  const float var = ss * (1.f / 1024.f) - mean * mean;
  const float rstd = rsqrtf(var + 1e-5f);
  const float4 g = ((const float4*)sc)[tid];
  const float4 b = ((const float4*)sh)[tid];
  ushort4 o;
  o.x = f2bf(g.x * (v.x - mean) * rstd + b.x);
  o.y = f2bf(g.y * (v.y - mean) * rstd + b.y);
  o.z = f2bf(g.z * (v.z - mean) * rstd + b.z);
  o.w = f2bf(g.w * (v.w - mean) * rstd + b.w);
  ((ushort4*)(out + (size_t)row * 1024))[tid] = o;
}

// ---------------- 128x128 bf16 GEMM, C = A[M,K] @ Bt[N,K]^T, fp32 accum ----------------
template <int MODE>
__global__ __launch_bounds__(256) void gemm_bf16(
    const u16* __restrict__ A, const u16* __restrict__ Bt, int M, int N, int K,
    void* __restrict__ outp, const float* __restrict__ aux,
    u16* __restrict__ qd, u16* __restrict__ kd, u16* __restrict__ vd) {
  __shared__ u16 lA[128 * 32];
  __shared__ u16 lB[128 * 32];
  const int tid = threadIdx.x;
  const int w = tid >> 6, lane = tid & 63;
  const int lo = lane & 15, hi = lane >> 4;
  const int tM = blockIdx.y * 128, tN = blockIdx.x * 128;
  const int wr = (w >> 1) << 6, wc = (w & 1) << 6;

  const u16 *sA[2], *sB[2];
  u16 *dA[2], *dB[2];
#pragma unroll
  for (int p = 0; p < 2; ++p) {
    const int c = p * 256 + tid;
    const int r = c >> 2, gs = (c & 3) ^ (r & 3);   // source-side XOR swizzle
    sA[p] = A + (size_t)(tM + r) * K + gs * 8;
    sB[p] = Bt + (size_t)(tN + r) * K + gs * 8;
    dA[p] = &lA[(p * 256 + w * 64) * 8];
    dB[p] = &lB[(p * 256 + w * 64) * 8];
  }

  fx4 acc[4][4];
#pragma unroll
  for (int m = 0; m < 4; ++m)
#pragma unroll
    for (int n = 0; n < 4; ++n) acc[m][n] = (fx4){0.f, 0.f, 0.f, 0.f};

  for (int kk = 0; kk < K; kk += 32) {
    __syncthreads();
#pragma unroll
    for (int p = 0; p < 2; ++p) {
      gload_lds16(sA[p] + kk, dA[p]);
      gload_lds16(sB[p] + kk, dB[p]);
    }
    __syncthreads();
    bf16x8 af[4], bfr[4];
#pragma unroll
    for (int m = 0; m < 4; ++m) {
      const int r = wr + m * 16 + lo;
      af[m] = *(const bf16x8*)&lA[r * 32 + ((hi ^ (r & 3)) << 3)];
    }
#pragma unroll
    for (int n = 0; n < 4; ++n) {
      const int r = wc + n * 16 + lo;
      bfr[n] = *(const bf16x8*)&lB[r * 32 + ((hi ^ (r & 3)) << 3)];
    }
#pragma unroll
    for (int m = 0; m < 4; ++m)
#pragma unroll
      for (int n = 0; n < 4; ++n) acc[m][n] = MFMA16(af[m], bfr[n], acc[m][n]);
  }

#pragma unroll
  for (int m = 0; m < 4; ++m) {
    const int rgb = tM + wr + m * 16 + hi * 4;
#pragma unroll
    for (int n = 0; n < 4; ++n) {
      const int cg = tN + wc + n * 16 + lo;
#pragma unroll
      for (int r = 0; r < 4; ++r) {
        const float v = acc[m][n][r];
        const int rg = rgb + r;
        if constexpr (MODE == 0) {
          const int which = cg >> 10, c = cg & 1023;
          const int head = c >> 6, dhi = c & 63;
          const int b = rg >> 11, sidx = rg & 2047;
          const int bh = b * 16 + head;
          const u16 bv = f2bf(v);
          if (which == 0)      qd[((size_t)bh * 2048 + sidx) * 64 + dhi] = bv;
          else if (which == 1) kd[((size_t)bh * 2048 + sidx) * 64 + dhi] = bv;
          else                 vd[((size_t)bh * 64 + dhi) * 2048 + sidx] = bv;
        } else if constexpr (MODE == 1) {
          float* o = (float*)outp;
          const size_t idx = (size_t)rg * 1024 + cg;
          o[idx] = aux[idx] + v;
        } else if constexpr (MODE == 2) {
          const float xx = v + aux[cg];
          const float t = xx + 0.044715f * xx * xx * xx;
          const float e = __expf(1.5957691216057308f * t);  // 2*sqrt(2/pi)
          const float th = 1.f - 2.f / (e + 1.f);
          ((u16*)outp)[(size_t)rg * 4096 + cg] = f2bf(0.5f * xx * (1.f + th));
        } else {
          float* o = (float*)outp;
          const size_t idx = (size_t)rg * 1024 + cg;
          o[idx] = o[idx] + v + aux[cg];
        }
      }
    }
  }
}

// ---------------- causal flash attention, bf16 MFMA, folded + LDS-staged ----------------
// grid: (8, BH). Block j does q-tiles j and 15-j (128 rows each), 4 waves x 32 rows.
// K/V tiles (64 keys) staged in double-buffered LDS shared by all 4 waves.
// Uniform work: (2j+2) + (32-2j) = 34 tiles per block.
__global__ __launch_bounds__(256) void attn_kernel(const u16* __restrict__ Q,
                                                   const u16* __restrict__ Kg,
                                                   const u16* __restrict__ Vt,
                                                   u16* __restrict__ ctx) {
  __shared__ u16 lK[2][64 * 64];
  __shared__ u16 lV[2][64 * 64];
  __shared__ u16 Plds[4][2048];
  const int tid = threadIdx.x;
  const int w = tid >> 6, lane = tid & 63;
  const int lo = lane & 15, hi = lane >> 4;
  const int j = blockIdx.x;
  const int bh = blockIdx.y;
  const u16* Qb = Q + (size_t)bh * 2048 * 64;
  const u16* Kb = Kg + (size_t)bh * 2048 * 64;
  const u16* Vb = Vt + (size_t)bh * 64 * 2048;
  u16* Pw = Plds[w];
  const int nt0 = 2 * j + 2;  // tiles for pass 0; pass 1 has 32-2j; total 34

  // staging address precompute: c = p*256+tid; row=c>>3; linear unit=c&7;
  // source unit = (c&7) ^ (row&7)  (XOR swizzle via pre-swizzled global source)
  int rowS[2], ugS[2];
#pragma unroll
  for (int p = 0; p < 2; ++p) {
    const int c = p * 256 + tid;
    rowS[p] = c >> 3;
    ugS[p] = (c & 7) ^ (rowS[p] & 7);
  }

#define STAGE(BUF, KB)                                                              \
  do {                                                                              \
    _Pragma("unroll") for (int p = 0; p < 2; ++p) {                                 \
      gload_lds16(Kb + (size_t)((KB) + rowS[p]) * 64 + ugS[p] * 8,                  \
                  &lK[BUF][(p * 256 + w * 64) * 8]);                                \
      gload_lds16(Vb + (size_t)rowS[p] * 2048 + (KB) + ugS[p] * 8,                  \
                  &lV[BUF][(p * 256 + w * 64) * 8]);                                \
    }                                                                               \
  } while (0)

  const int b = bh >> 4, h = bh & 15;

  int qt = j;
  int qbw = qt * 128 + w * 32;

  bf16x8 qf[2][2];
#pragma unroll
  for (int rt = 0; rt < 2; ++rt)
#pragma unroll
    for (int kc = 0; kc < 2; ++kc)
      qf[rt][kc] = *(const bf16x8*)&Qb[(size_t)(qbw + rt * 16 + lo) * 64 + kc * 32 + hi * 8];

  fx4 accO[2][4];
  float mrow[2][4], lrow[2][4];
#pragma unroll
  for (int rt = 0; rt < 2; ++rt)
#pragma unroll
    for (int t = 0; t < 4; ++t) {
      accO[rt][t] = (fx4){0.f, 0.f, 0.f, 0.f};
      mrow[rt][t] = -1e30f;
      lrow[rt][t] = 0.f;
    }

  // prologue: stage tile 0
  STAGE(0, 0);
  __syncthreads();

  int buf = 0;
  for (int t = 0; t < 34; ++t) {
    // issue next tile's loads (overlaps with compute below)
    if (t + 1 < 34) {
      const int tn = t + 1;
      const int kbn = (tn < nt0 ? tn : tn - nt0) * 64;
      STAGE(buf ^ 1, kbn);
    }
    // pass boundary: finish pass 0, switch to q-tile 15-j
    if (t == nt0) {
#pragma unroll
      for (int rt = 0; rt < 2; ++rt)
#pragma unroll
        for (int t2 = 0; t2 < 4; ++t2)
#pragma unroll
          for (int r = 0; r < 4; ++r) {
            const int rg = b * 2048 + qbw + rt * 16 + hi * 4 + r;
            const int cg = h * 64 + t2 * 16 + lo;
            ctx[(size_t)rg * 1024 + cg] = f2bf(accO[rt][t2][r] / lrow[rt][r]);
          }
      qt = 15 - j;
      qbw = qt * 128 + w * 32;
#pragma unroll
      for (int rt = 0; rt < 2; ++rt)
#pragma unroll
        for (int kc = 0; kc < 2; ++kc)
          qf[rt][kc] =
              *(const bf16x8*)&Qb[(size_t)(qbw + rt * 16 + lo) * 64 + kc * 32 + hi * 8];
#pragma unroll
      for (int rt = 0; rt < 2; ++rt)
#pragma unroll
        for (int t2 = 0; t2 < 4; ++t2) {
          accO[rt][t2] = (fx4){0.f, 0.f, 0.f, 0.f};
          mrow[rt][t2] = -1e30f;
          lrow[rt][t2] = 0.f;
        }
    }
    const int kb = (t < nt0 ? t : t - nt0) * 64;
    if (kb <= qbw + 31) {
      const u16* lKb = lK[buf];
      const u16* lVb = lV[buf];
      fx4 s[2][4];
#pragma unroll
      for (int tt = 0; tt < 4; ++tt) {
        const int r = tt * 16 + lo;
        const bf16x8 kf0 = *(const bf16x8*)&lKb[r * 64 + ((hi ^ (r & 7)) << 3)];
        const bf16x8 kf1 = *(const bf16x8*)&lKb[r * 64 + (((4 + hi) ^ (r & 7)) << 3)];
#pragma unroll
        for (int rt = 0; rt < 2; ++rt) {
          fx4 z = (fx4){0.f, 0.f, 0.f, 0.f};
          z = MFMA16(qf[rt][0], kf0, z);
          z = MFMA16(qf[rt][1], kf1, z);
          s[rt][tt] = z;
        }
      }
#pragma unroll
      for (int rt = 0; rt < 2; ++rt) {
#pragma unroll
        for (int tt = 0; tt < 4; ++tt)
#pragma unroll
          for (int r = 0; r < 4; ++r) {
            const int key = kb + tt * 16 + lo;
            const int qr = qbw + rt * 16 + hi * 4 + r;
            const float sv = s[rt][tt][r] * 0.125f;
            s[rt][tt][r] = (key > qr) ? -1e30f : sv;
          }
        float mt[4];
#pragma unroll
        for (int r = 0; r < 4; ++r)
          mt[r] = fmaxf(fmaxf(s[rt][0][r], s[rt][1][r]), fmaxf(s[rt][2][r], s[rt][3][r]));
#pragma unroll
        for (int d = 8; d >= 1; d >>= 1)
#pragma unroll
          for (int r = 0; r < 4; ++r) mt[r] = fmaxf(mt[r], __shfl_xor(mt[r], d));
        float fsc[4], la[4];
#pragma unroll
        for (int r = 0; r < 4; ++r) {
          const float mn = fmaxf(mrow[rt][r], mt[r]);
          fsc[r] = __expf(mrow[rt][r] - mn);
          mrow[rt][r] = mn;
          la[r] = 0.f;
        }
#pragma unroll
        for (int tt = 0; tt < 4; ++tt)
#pragma unroll
          for (int r = 0; r < 4; ++r) {
            const float p = __expf(s[rt][tt][r] - mrow[rt][r]);
            s[rt][tt][r] = p;
            la[r] += p;
          }
#pragma unroll
        for (int d = 8; d >= 1; d >>= 1)
#pragma unroll
          for (int r = 0; r < 4; ++r) la[r] += __shfl_xor(la[r], d);
#pragma unroll
        for (int r = 0; r < 4; ++r) lrow[rt][r] = lrow[rt][r] * fsc[r] + la[r];
#pragma unroll
        for (int t2 = 0; t2 < 4; ++t2)
#pragma unroll
          for (int r = 0; r < 4; ++r) accO[rt][t2][r] *= fsc[r];
        // P -> LDS (XOR-swizzled)
#pragma unroll
        for (int tt = 0; tt < 4; ++tt)
#pragma unroll
          for (int r = 0; r < 4; ++r) {
            const int row = rt * 16 + hi * 4 + r;
            const int colB = (tt * 16 + lo) * 2;
            Pw[(row * 128 + (colB ^ ((row & 7) << 4))) >> 1] = f2bf(s[rt][tt][r]);
          }
      }
      asm volatile("s_waitcnt lgkmcnt(0)" ::: "memory");
      bf16x8 pf[2][2];
#pragma unroll
      for (int rt = 0; rt < 2; ++rt)
#pragma unroll
        for (int kc = 0; kc < 2; ++kc) {
          const int row = rt * 16 + lo;
          const int colB = kc * 64 + hi * 16;
          pf[rt][kc] =
              *(const bf16x8*)((const char*)Pw + row * 128 + (colB ^ ((row & 7) << 4)));
        }
#pragma unroll
      for (int t2 = 0; t2 < 4; ++t2) {
        const int r2 = t2 * 16 + lo;
        const bf16x8 vf0 = *(const bf16x8*)&lVb[r2 * 64 + ((hi ^ (r2 & 7)) << 3)];
        const bf16x8 vf1 = *(const bf16x8*)&lVb[r2 * 64 + (((4 + hi) ^ (r2 & 7)) << 3)];
#pragma unroll
        for (int rt = 0; rt < 2; ++rt) {
          accO[rt][t2] = MFMA16(pf[rt][0], vf0, accO[rt][t2]);
          accO[rt][t2] = MFMA16(pf[rt][1], vf1, accO[rt][t2]);
        }
      }
    }
    __syncthreads();  // drains vmcnt (staged loads) + lgkm; all waves done with buf
    buf ^= 1;
  }
  // epilogue: write pass-1 output
#pragma unroll
  for (int rt = 0; rt < 2; ++rt)
#pragma unroll
    for (int t2 = 0; t2 < 4; ++t2)
#pragma unroll
      for (int r = 0; r < 4; ++r) {
        const int rg = b * 2048 + qbw + rt * 16 + hi * 4 + r;
        const int cg = h * 64 + t2 * 16 + lo;
        ctx[(size_t)rg * 1024 + cg] = f2bf(accO[rt][t2][r] / lrow[rt][r]);
      }
#undef STAGE
}

// ---------------- host ----------------
extern "C" void kernel_launch(void* const* d_in, const int* in_sizes, int n_in,
                              void* d_out, int out_size, void* d_ws, size_t ws_size,
                              hipStream_t stream) {
  const float* X    = (const float*)d_in[0];
  const float* Wq   = (const float*)d_in[1];
  const float* Wk   = (const float*)d_in[2];
  const float* Wv   = (const float*)d_in[3];
  const float* Wo   = (const float*)d_in[4];
  const float* W1   = (const float*)d_in[5];
  const float* b1   = (const float*)d_in[6];
  const float* W2   = (const float*)d_in[7];
  const float* b2   = (const float*)d_in[8];
  const float* ln1s = (const float*)d_in[9];
  const float* ln1b = (const float*)d_in[10];
  const float* ln2s = (const float*)d_in[11];
  const float* ln2b = (const float*)d_in[12];

  const size_t SZ_WQKVT = 3072UL * 1024;
  const size_t SZ_WOT   = 1024UL * 1024;
  const size_t SZ_W1T   = 4096UL * 1024;
  const size_t SZ_W2T   = 1024UL * 4096;
  const size_t SZ_H     = 8192UL * 1024;
  const size_t SZ_QKV   = 64UL * 2048 * 64;

  u16* WqkvT = (u16*)d_ws;
  u16* WoT   = WqkvT + SZ_WQKVT;
  u16* W1T   = WoT + SZ_WOT;
  u16* W2T   = W1T + SZ_W1T;
  u16* hbuf  = W2T + SZ_W2T;
  u16* qbuf  = hbuf + SZ_H;
  u16* kbuf  = qbuf + SZ_QKV;
  u16* vbuf  = kbuf + SZ_QKV;
  u16* gbuf  = vbuf + SZ_QKV;
  u16* ctx   = hbuf;  // reuse (h dead after QKV GEMM)
  u16* h2    = qbuf;  // reuse (q/k dead after attention)

  float* out = (float*)d_out;
  dim3 blk(256);

  // weights -> bf16 transposed
  tcvt<<<dim3(32, 32), blk, 0, stream>>>(Wq, WqkvT, 1024, 1024);
  tcvt<<<dim3(32, 32), blk, 0, stream>>>(Wk, WqkvT + 1024 * 1024, 1024, 1024);
  tcvt<<<dim3(32, 32), blk, 0, stream>>>(Wv, WqkvT + 2 * 1024 * 1024, 1024, 1024);
  tcvt<<<dim3(32, 32), blk, 0, stream>>>(Wo, WoT, 1024, 1024);
  tcvt<<<dim3(128, 32), blk, 0, stream>>>(W1, W1T, 1024, 4096);
  tcvt<<<dim3(32, 128), blk, 0, stream>>>(W2, W2T, 4096, 1024);

  // LN1
  ln_kernel<<<8192, blk, 0, stream>>>(X, ln1s, ln1b, hbuf);
  // QKV
  gemm_bf16<0><<<dim3(24, 64), blk, 0, stream>>>(hbuf, WqkvT, 8192, 3072, 1024,
                                                 nullptr, nullptr, qbuf, kbuf, vbuf);
  // attention (folded, LDS-staged)
  attn_kernel<<<dim3(8, 64), blk, 0, stream>>>(qbuf, kbuf, vbuf, ctx);
  // Wo + residual -> d_out (X1)
  gemm_bf16<1><<<dim3(8, 64), blk, 0, stream>>>(ctx, WoT, 8192, 1024, 1024,
                                                out, X, nullptr, nullptr, nullptr);
  // LN2
  ln_kernel<<<8192, blk, 0, stream>>>(out, ln2s, ln2b, h2);
  // MLP1: gelu(h2@W1 + b1)
  gemm_bf16<2><<<dim3(32, 64), blk, 0, stream>>>(h2, W1T, 8192, 4096, 1024,
                                                 gbuf, b1, nullptr, nullptr, nullptr);
  // MLP2: d_out = X1 + g@W2 + b2
  gemm_bf16<3><<<dim3(8, 64), blk, 0, stream>>>(gbuf, W2T, 8192, 1024, 4096,
                                                out, b2, nullptr, nullptr, nullptr);
}

// Round 5
// 502.311 us; speedup vs baseline: 1.5626x; 1.0337x over previous
//
#include <hip/hip_runtime.h>

typedef unsigned short u16;
typedef __attribute__((ext_vector_type(8))) short bf16x8;
typedef __attribute__((ext_vector_type(4))) float fx4;

#define MFMA16(a, b, c) __builtin_amdgcn_mfma_f32_16x16x32_bf16((a), (b), (c), 0, 0, 0)

__device__ __forceinline__ u16 f2bf(float f) {
  unsigned u = __float_as_uint(f);
  u += 0x7fffu + ((u >> 16) & 1u);
  return (u16)(u >> 16);
}

__device__ __forceinline__ void gload_lds16(const void* g, void* l) {
  __builtin_amdgcn_global_load_lds((const __attribute__((address_space(1))) void*)g,
                                   (__attribute__((address_space(3))) void*)l,
                                   16, 0, 0);
}

// ---------------- transpose + fp32->bf16 convert: dst[c][r] = src[r][c] ----------------
__global__ __launch_bounds__(256) void tcvt(const float* __restrict__ src,
                                            u16* __restrict__ dst, int R, int C) {
  __shared__ float t[32][33];
  const int tx = threadIdx.x & 31, ty = threadIdx.x >> 5;  // 32x8
  const int bx = blockIdx.x, by = blockIdx.y;
#pragma unroll
  for (int i = 0; i < 4; ++i)
    t[ty + i * 8][tx] = src[(size_t)(by * 32 + ty + i * 8) * C + bx * 32 + tx];
  __syncthreads();
#pragma unroll
  for (int i = 0; i < 4; ++i)
    dst[(size_t)(bx * 32 + ty + i * 8) * R + by * 32 + tx] = f2bf(t[tx][ty + i * 8]);
}

// ---------------- layernorm: fp32 [rows][1024] -> bf16 ----------------
__global__ __launch_bounds__(256) void ln_kernel(const float* __restrict__ x,
                                                 const float* __restrict__ sc,
                                                 const float* __restrict__ sh,
                                                 u16* __restrict__ out) {
  const int row = blockIdx.x, tid = threadIdx.x;
  const float4 v = ((const float4*)(x + (size_t)row * 1024))[tid];
  float s = v.x + v.y + v.z + v.w;
  float ss = v.x * v.x + v.y * v.y + v.z * v.z + v.w * v.w;
#pragma unroll
  for (int d = 32; d >= 1; d >>= 1) {
    s += __shfl_xor(s, d);
    ss += __shfl_xor(ss, d);
  }
  __shared__ float rs[4], rq[4];
  const int w = tid >> 6;
  if ((tid & 63) == 0) { rs[w] = s; rq[w] = ss; }
  __syncthreads();
  s = rs[0] + rs[1] + rs[2] + rs[3];
  ss = rq[0] + rq[1] + rq[2] + rq[3];
  const float mean = s * (1.f / 1024.f);
  const float var = ss * (1.f / 1024.f) - mean * mean;
  const float rstd = rsqrtf(var + 1e-5f);
  const float4 g = ((const float4*)sc)[tid];
  const float4 b = ((const float4*)sh)[tid];
  ushort4 o;
  o.x = f2bf(g.x * (v.x - mean) * rstd + b.x);
  o.y = f2bf(g.y * (v.y - mean) * rstd + b.y);
  o.z = f2bf(g.z * (v.z - mean) * rstd + b.z);
  o.w = f2bf(g.w * (v.w - mean) * rstd + b.w);
  ((ushort4*)(out + (size_t)row * 1024))[tid] = o;
}

// ---------------- 128x128 bf16 GEMM, C = A[M,K] @ Bt[N,K]^T, fp32 accum ----------------
template <int MODE>
__global__ __launch_bounds__(256) void gemm_bf16(
    const u16* __restrict__ A, const u16* __restrict__ Bt, int M, int N, int K,
    void* __restrict__ outp, const float* __restrict__ aux,
    u16* __restrict__ qd, u16* __restrict__ kd, u16* __restrict__ vd) {
  __shared__ u16 lA[128 * 32];
  __shared__ u16 lB[128 * 32];
  const int tid = threadIdx.x;
  const int w = tid >> 6, lane = tid & 63;
  const int lo = lane & 15, hi = lane >> 4;
  const int tM = blockIdx.y * 128, tN = blockIdx.x * 128;
  const int wr = (w >> 1) << 6, wc = (w & 1) << 6;

  const u16 *sA[2], *sB[2];
  u16 *dA[2], *dB[2];
#pragma unroll
  for (int p = 0; p < 2; ++p) {
    const int c = p * 256 + tid;
    const int r = c >> 2, gs = (c & 3) ^ (r & 3);   // source-side XOR swizzle
    sA[p] = A + (size_t)(tM + r) * K + gs * 8;
    sB[p] = Bt + (size_t)(tN + r) * K + gs * 8;
    dA[p] = &lA[(p * 256 + w * 64) * 8];
    dB[p] = &lB[(p * 256 + w * 64) * 8];
  }

  fx4 acc[4][4];
#pragma unroll
  for (int m = 0; m < 4; ++m)
#pragma unroll
    for (int n = 0; n < 4; ++n) acc[m][n] = (fx4){0.f, 0.f, 0.f, 0.f};

  for (int kk = 0; kk < K; kk += 32) {
    __syncthreads();
#pragma unroll
    for (int p = 0; p < 2; ++p) {
      gload_lds16(sA[p] + kk, dA[p]);
      gload_lds16(sB[p] + kk, dB[p]);
    }
    __syncthreads();
    bf16x8 af[4], bfr[4];
#pragma unroll
    for (int m = 0; m < 4; ++m) {
      const int r = wr + m * 16 + lo;
      af[m] = *(const bf16x8*)&lA[r * 32 + ((hi ^ (r & 3)) << 3)];
    }
#pragma unroll
    for (int n = 0; n < 4; ++n) {
      const int r = wc + n * 16 + lo;
      bfr[n] = *(const bf16x8*)&lB[r * 32 + ((hi ^ (r & 3)) << 3)];
    }
#pragma unroll
    for (int m = 0; m < 4; ++m)
#pragma unroll
      for (int n = 0; n < 4; ++n) acc[m][n] = MFMA16(af[m], bfr[n], acc[m][n]);
  }

#pragma unroll
  for (int m = 0; m < 4; ++m) {
    const int rgb = tM + wr + m * 16 + hi * 4;
#pragma unroll
    for (int n = 0; n < 4; ++n) {
      const int cg = tN + wc + n * 16 + lo;
#pragma unroll
      for (int r = 0; r < 4; ++r) {
        const float v = acc[m][n][r];
        const int rg = rgb + r;
        if constexpr (MODE == 0) {
          const int which = cg >> 10, c = cg & 1023;
          const int head = c >> 6, dhi = c & 63;
          const int b = rg >> 11, sidx = rg & 2047;
          const int bh = b * 16 + head;
          const u16 bv = f2bf(v);
          if (which == 0)      qd[((size_t)bh * 2048 + sidx) * 64 + dhi] = bv;
          else if (which == 1) kd[((size_t)bh * 2048 + sidx) * 64 + dhi] = bv;
          else                 vd[((size_t)bh * 64 + dhi) * 2048 + sidx] = bv;
        } else if constexpr (MODE == 1) {
          float* o = (float*)outp;
          const size_t idx = (size_t)rg * 1024 + cg;
          o[idx] = aux[idx] + v;
        } else if constexpr (MODE == 2) {
          const float xx = v + aux[cg];
          const float t = xx + 0.044715f * xx * xx * xx;
          const float e = __expf(1.5957691216057308f * t);  // 2*sqrt(2/pi)
          const float th = 1.f - 2.f / (e + 1.f);
          ((u16*)outp)[(size_t)rg * 4096 + cg] = f2bf(0.5f * xx * (1.f + th));
        } else {
          float* o = (float*)outp;
          const size_t idx = (size_t)rg * 1024 + cg;
          o[idx] = o[idx] + v + aux[cg];
        }
      }
    }
  }
}

// ---------------- causal flash attention, bf16 MFMA ----------------
// grid: (BH, 8), 512 threads = 8 waves. Block (bh, j) does q-tiles j and 15-j
// (128 rows each); wave w owns 16 q-rows. K/V (64-key tiles) double-buffered in
// LDS shared by all 8 waves. Uniform work: (2j+2)+(32-2j) = 34 tiles/block.
// bh = blockIdx.x so all 8 blocks of one bh share an XCD (wgid%8 = bh%8).
__global__ __launch_bounds__(512) void attn_kernel(const u16* __restrict__ Q,
                                                   const u16* __restrict__ Kg,
                                                   const u16* __restrict__ Vt,
                                                   u16* __restrict__ ctx) {
  __shared__ u16 lK[2][64 * 64];
  __shared__ u16 lV[2][64 * 64];
  __shared__ u16 Plds[8][16 * 64];
  const int tid = threadIdx.x;
  const int w = tid >> 6, lane = tid & 63;
  const int lo = lane & 15, hi = lane >> 4;
  const int bh = blockIdx.x;
  const int j = blockIdx.y;
  const u16* Qb = Q + (size_t)bh * 2048 * 64;
  const u16* Kb = Kg + (size_t)bh * 2048 * 64;
  const u16* Vb = Vt + (size_t)bh * 64 * 2048;
  u16* Pw = Plds[w];
  const int nt0 = 2 * j + 2;  // pass-0 tiles; pass 1 has 32-2j; total 34

  // staging: 512 threads x 16B = one full 64x64 bf16 tile per issue.
  // linear dest slot = tid (row=tid>>3, unit=tid&7); source unit XOR-swizzled.
  const int rowS = tid >> 3;
  const int ugS = (tid & 7) ^ (rowS & 7);

#define STAGE(BUF, KB)                                                       \
  do {                                                                       \
    gload_lds16(Kb + (size_t)((KB) + rowS) * 64 + ugS * 8, &lK[BUF][tid * 8]); \
    gload_lds16(Vb + (size_t)rowS * 2048 + (KB) + ugS * 8, &lV[BUF][tid * 8]); \
  } while (0)

  const int b = bh >> 4, h = bh & 15;
  const float SCALE = 0.18033688011112042f;  // 0.125 * log2(e)

  int qt = j;
  int qw = qt * 128 + w * 16;  // this wave's first q row

  bf16x8 qf[2];
#pragma unroll
  for (int kc = 0; kc < 2; ++kc)
    qf[kc] = *(const bf16x8*)&Qb[(size_t)(qw + lo) * 64 + kc * 32 + hi * 8];

  fx4 accO[4];
  float mrow[4], lrow[4];
#pragma unroll
  for (int t2 = 0; t2 < 4; ++t2) {
    accO[t2] = (fx4){0.f, 0.f, 0.f, 0.f};
    mrow[t2] = -1e30f;
    lrow[t2] = 0.f;
  }

  STAGE(0, 0);
  __syncthreads();

  int buf = 0;
  for (int t = 0; t < 34; ++t) {
    if (t + 1 < 34) {
      const int tn = t + 1;
      const int kbn = (tn < nt0 ? tn : tn - nt0) * 64;
      STAGE(buf ^ 1, kbn);
    }
    if (t == nt0) {  // pass boundary: flush q-tile j, switch to 15-j
#pragma unroll
      for (int t2 = 0; t2 < 4; ++t2)
#pragma unroll
        for (int r = 0; r < 4; ++r) {
          const int rg = b * 2048 + qw + hi * 4 + r;
          const int cg = h * 64 + t2 * 16 + lo;
          ctx[(size_t)rg * 1024 + cg] = f2bf(accO[t2][r] / lrow[r]);
        }
      qt = 15 - j;
      qw = qt * 128 + w * 16;
#pragma unroll
      for (int kc = 0; kc < 2; ++kc)
        qf[kc] = *(const bf16x8*)&Qb[(size_t)(qw + lo) * 64 + kc * 32 + hi * 8];
#pragma unroll
      for (int t2 = 0; t2 < 4; ++t2) {
        accO[t2] = (fx4){0.f, 0.f, 0.f, 0.f};
        mrow[t2] = -1e30f;
        lrow[t2] = 0.f;
      }
    }
    const int kb = (t < nt0 ? t : t - nt0) * 64;
    if (kb <= qw + 15) {
      const u16* lKb = lK[buf];
      const u16* lVb = lV[buf];
      fx4 s[4];
#pragma unroll
      for (int tt = 0; tt < 4; ++tt) {
        const int r = tt * 16 + lo;
        const bf16x8 kf0 = *(const bf16x8*)&lKb[r * 64 + ((hi ^ (r & 7)) << 3)];
        const bf16x8 kf1 = *(const bf16x8*)&lKb[r * 64 + (((4 + hi) ^ (r & 7)) << 3)];
        fx4 z = (fx4){0.f, 0.f, 0.f, 0.f};
        z = MFMA16(qf[0], kf0, z);
        z = MFMA16(qf[1], kf1, z);
        s[tt] = z;
      }
      // scale (log2 domain); mask only the diagonal tile (wave-uniform test)
      if (kb + 63 > qw) {
#pragma unroll
        for (int tt = 0; tt < 4; ++tt)
#pragma unroll
          for (int r = 0; r < 4; ++r) {
            const int key = kb + tt * 16 + lo;
            const int qr = qw + hi * 4 + r;
            s[tt][r] = (key > qr) ? -1e30f : s[tt][r] * SCALE;
          }
      } else {
#pragma unroll
        for (int tt = 0; tt < 4; ++tt)
#pragma unroll
          for (int r = 0; r < 4; ++r) s[tt][r] *= SCALE;
      }
      float mt[4];
#pragma unroll
      for (int r = 0; r < 4; ++r)
        mt[r] = fmaxf(fmaxf(s[0][r], s[1][r]), fmaxf(s[2][r], s[3][r]));
#pragma unroll
      for (int d = 8; d >= 1; d >>= 1)
#pragma unroll
        for (int r = 0; r < 4; ++r) mt[r] = fmaxf(mt[r], __shfl_xor(mt[r], d));
      // defer-max (THR = 8 in log2 units -> P bounded by 2^8)
      bool ok = true;
#pragma unroll
      for (int r = 0; r < 4; ++r) ok = ok && (mt[r] <= mrow[r] + 8.f);
      if (!__all(ok)) {
#pragma unroll
        for (int r = 0; r < 4; ++r) {
          const float mn = fmaxf(mrow[r], mt[r]);
          const float fsc = exp2f(mrow[r] - mn);
          mrow[r] = mn;
          lrow[r] *= fsc;
#pragma unroll
          for (int t2 = 0; t2 < 4; ++t2) accO[t2][r] *= fsc;
        }
      }
      float la[4] = {0.f, 0.f, 0.f, 0.f};
#pragma unroll
      for (int tt = 0; tt < 4; ++tt)
#pragma unroll
        for (int r = 0; r < 4; ++r) {
          const float p = exp2f(s[tt][r] - mrow[r]);
          s[tt][r] = p;
          la[r] += p;
        }
#pragma unroll
      for (int d = 8; d >= 1; d >>= 1)
#pragma unroll
        for (int r = 0; r < 4; ++r) la[r] += __shfl_xor(la[r], d);
#pragma unroll
      for (int r = 0; r < 4; ++r) lrow[r] += la[r];
      // P -> LDS (wave-private, XOR-swizzled rows)
#pragma unroll
      for (int tt = 0; tt < 4; ++tt)
#pragma unroll
        for (int r = 0; r < 4; ++r) {
          const int row = hi * 4 + r;
          const int colB = (tt * 16 + lo) * 2;
          Pw[(row * 128 + (colB ^ ((row & 7) << 4))) >> 1] = f2bf(s[tt][r]);
        }
      asm volatile("s_waitcnt lgkmcnt(0)" ::: "memory");
      bf16x8 pf[2];
#pragma unroll
      for (int kc = 0; kc < 2; ++kc) {
        const int row = lo;
        const int colB = kc * 64 + hi * 16;
        pf[kc] = *(const bf16x8*)((const char*)Pw + row * 128 + (colB ^ ((row & 7) << 4)));
      }
#pragma unroll
      for (int t2 = 0; t2 < 4; ++t2) {
        const int r2 = t2 * 16 + lo;
        const bf16x8 vf0 = *(const bf16x8*)&lVb[r2 * 64 + ((hi ^ (r2 & 7)) << 3)];
        const bf16x8 vf1 = *(const bf16x8*)&lVb[r2 * 64 + (((4 + hi) ^ (r2 & 7)) << 3)];
        accO[t2] = MFMA16(pf[0], vf0, accO[t2]);
        accO[t2] = MFMA16(pf[1], vf1, accO[t2]);
      }
    }
    __syncthreads();  // drains vmcnt: staged tile landed; all waves done with buf
    buf ^= 1;
  }
  // epilogue: write pass-1 output
#pragma unroll
  for (int t2 = 0; t2 < 4; ++t2)
#pragma unroll
    for (int r = 0; r < 4; ++r) {
      const int rg = b * 2048 + qw + hi * 4 + r;
      const int cg = h * 64 + t2 * 16 + lo;
      ctx[(size_t)rg * 1024 + cg] = f2bf(accO[t2][r] / lrow[r]);
    }
#undef STAGE
}

// ---------------- host ----------------
extern "C" void kernel_launch(void* const* d_in, const int* in_sizes, int n_in,
                              void* d_out, int out_size, void* d_ws, size_t ws_size,
                              hipStream_t stream) {
  const float* X    = (const float*)d_in[0];
  const float* Wq   = (const float*)d_in[1];
  const float* Wk   = (const float*)d_in[2];
  const float* Wv   = (const float*)d_in[3];
  const float* Wo   = (const float*)d_in[4];
  const float* W1   = (const float*)d_in[5];
  const float* b1   = (const float*)d_in[6];
  const float* W2   = (const float*)d_in[7];
  const float* b2   = (const float*)d_in[8];
  const float* ln1s = (const float*)d_in[9];
  const float* ln1b = (const float*)d_in[10];
  const float* ln2s = (const float*)d_in[11];
  const float* ln2b = (const float*)d_in[12];

  const size_t SZ_WQKVT = 3072UL * 1024;
  const size_t SZ_WOT   = 1024UL * 1024;
  const size_t SZ_W1T   = 4096UL * 1024;
  const size_t SZ_W2T   = 1024UL * 4096;
  const size_t SZ_H     = 8192UL * 1024;
  const size_t SZ_QKV   = 64UL * 2048 * 64;

  u16* WqkvT = (u16*)d_ws;
  u16* WoT   = WqkvT + SZ_WQKVT;
  u16* W1T   = WoT + SZ_WOT;
  u16* W2T   = W1T + SZ_W1T;
  u16* hbuf  = W2T + SZ_W2T;
  u16* qbuf  = hbuf + SZ_H;
  u16* kbuf  = qbuf + SZ_QKV;
  u16* vbuf  = kbuf + SZ_QKV;
  u16* gbuf  = vbuf + SZ_QKV;
  u16* ctx   = hbuf;  // reuse (h dead after QKV GEMM)
  u16* h2    = qbuf;  // reuse (q/k dead after attention)

  float* out = (float*)d_out;
  dim3 blk(256);

  // weights -> bf16 transposed
  tcvt<<<dim3(32, 32), blk, 0, stream>>>(Wq, WqkvT, 1024, 1024);
  tcvt<<<dim3(32, 32), blk, 0, stream>>>(Wk, WqkvT + 1024 * 1024, 1024, 1024);
  tcvt<<<dim3(32, 32), blk, 0, stream>>>(Wv, WqkvT + 2 * 1024 * 1024, 1024, 1024);
  tcvt<<<dim3(32, 32), blk, 0, stream>>>(Wo, WoT, 1024, 1024);
  tcvt<<<dim3(128, 32), blk, 0, stream>>>(W1, W1T, 1024, 4096);
  tcvt<<<dim3(32, 128), blk, 0, stream>>>(W2, W2T, 4096, 1024);

  // LN1
  ln_kernel<<<8192, blk, 0, stream>>>(X, ln1s, ln1b, hbuf);
  // QKV
  gemm_bf16<0><<<dim3(24, 64), blk, 0, stream>>>(hbuf, WqkvT, 8192, 3072, 1024,
                                                 nullptr, nullptr, qbuf, kbuf, vbuf);
  // attention (folded, 8-wave, LDS-staged, XCD-local)
  attn_kernel<<<dim3(64, 8), dim3(512), 0, stream>>>(qbuf, kbuf, vbuf, ctx);
  // Wo + residual -> d_out (X1)
  gemm_bf16<1><<<dim3(8, 64), blk, 0, stream>>>(ctx, WoT, 8192, 1024, 1024,
                                                out, X, nullptr, nullptr, nullptr);
  // LN2
  ln_kernel<<<8192, blk, 0, stream>>>(out, ln2s, ln2b, h2);
  // MLP1: gelu(h2@W1 + b1)
  gemm_bf16<2><<<dim3(32, 64), blk, 0, stream>>>(h2, W1T, 8192, 4096, 1024,
                                                 gbuf, b1, nullptr, nullptr, nullptr);
  // MLP2: d_out = X1 + g@W2 + b2
  gemm_bf16<3><<<dim3(8, 64), blk, 0, stream>>>(gbuf, W2T, 8192, 1024, 4096,
                                                out, b2, nullptr, nullptr, nullptr);
}

// Round 6
// 480.819 us; speedup vs baseline: 1.6325x; 1.0447x over previous
//
#include <hip/hip_runtime.h>

typedef unsigned short u16;
typedef __attribute__((ext_vector_type(8))) short bf16x8;
typedef __attribute__((ext_vector_type(4))) float fx4;

#define MFMA16(a, b, c) __builtin_amdgcn_mfma_f32_16x16x32_bf16((a), (b), (c), 0, 0, 0)

__device__ __forceinline__ u16 f2bf(float f) {
  unsigned u = __float_as_uint(f);
  u += 0x7fffu + ((u >> 16) & 1u);
  return (u16)(u >> 16);
}

__device__ __forceinline__ void gload_lds16(const void* g, void* l) {
  __builtin_amdgcn_global_load_lds((const __attribute__((address_space(1))) void*)g,
                                   (__attribute__((address_space(3))) void*)l,
                                   16, 0, 0);
}

// ---------------- transpose + fp32->bf16 convert: dst[c][r] = src[r][c] ----------------
__global__ __launch_bounds__(256) void tcvt(const float* __restrict__ src,
                                            u16* __restrict__ dst, int R, int C) {
  __shared__ float t[32][33];
  const int tx = threadIdx.x & 31, ty = threadIdx.x >> 5;  // 32x8
  const int bx = blockIdx.x, by = blockIdx.y;
#pragma unroll
  for (int i = 0; i < 4; ++i)
    t[ty + i * 8][tx] = src[(size_t)(by * 32 + ty + i * 8) * C + bx * 32 + tx];
  __syncthreads();
#pragma unroll
  for (int i = 0; i < 4; ++i)
    dst[(size_t)(bx * 32 + ty + i * 8) * R + by * 32 + tx] = f2bf(t[tx][ty + i * 8]);
}

// ---------------- layernorm: fp32 [rows][1024] -> bf16 ----------------
__global__ __launch_bounds__(256) void ln_kernel(const float* __restrict__ x,
                                                 const float* __restrict__ sc,
                                                 const float* __restrict__ sh,
                                                 u16* __restrict__ out) {
  const int row = blockIdx.x, tid = threadIdx.x;
  const float4 v = ((const float4*)(x + (size_t)row * 1024))[tid];
  float s = v.x + v.y + v.z + v.w;
  float ss = v.x * v.x + v.y * v.y + v.z * v.z + v.w * v.w;
#pragma unroll
  for (int d = 32; d >= 1; d >>= 1) {
    s += __shfl_xor(s, d);
    ss += __shfl_xor(ss, d);
  }
  __shared__ float rs[4], rq[4];
  const int w = tid >> 6;
  if ((tid & 63) == 0) { rs[w] = s; rq[w] = ss; }
  __syncthreads();
  s = rs[0] + rs[1] + rs[2] + rs[3];
  ss = rq[0] + rq[1] + rq[2] + rq[3];
  const float mean = s * (1.f / 1024.f);
  const float var = ss * (1.f / 1024.f) - mean * mean;
  const float rstd = rsqrtf(var + 1e-5f);
  const float4 g = ((const float4*)sc)[tid];
  const float4 b = ((const float4*)sh)[tid];
  ushort4 o;
  o.x = f2bf(g.x * (v.x - mean) * rstd + b.x);
  o.y = f2bf(g.y * (v.y - mean) * rstd + b.y);
  o.z = f2bf(g.z * (v.z - mean) * rstd + b.z);
  o.w = f2bf(g.w * (v.w - mean) * rstd + b.w);
  ((ushort4*)(out + (size_t)row * 1024))[tid] = o;
}

// ---------------- 128x128 bf16 GEMM (kept for Wo / MLP2) ----------------
// MODE 1: d_out = X + acc (fp32); MODE 3: d_out += acc + b2 (fp32 in-place RMW)
template <int MODE>
__global__ __launch_bounds__(256) void gemm_bf16(
    const u16* __restrict__ A, const u16* __restrict__ Bt, int M, int N, int K,
    void* __restrict__ outp, const float* __restrict__ aux,
    u16* __restrict__ qd, u16* __restrict__ kd, u16* __restrict__ vd) {
  __shared__ u16 lA[128 * 32];
  __shared__ u16 lB[128 * 32];
  const int tid = threadIdx.x;
  const int w = tid >> 6, lane = tid & 63;
  const int lo = lane & 15, hi = lane >> 4;
  const int tM = blockIdx.y * 128, tN = blockIdx.x * 128;
  const int wr = (w >> 1) << 6, wc = (w & 1) << 6;

  const u16 *sA[2], *sB[2];
  u16 *dA[2], *dB[2];
#pragma unroll
  for (int p = 0; p < 2; ++p) {
    const int c = p * 256 + tid;
    const int r = c >> 2, gs = (c & 3) ^ (r & 3);   // source-side XOR swizzle
    sA[p] = A + (size_t)(tM + r) * K + gs * 8;
    sB[p] = Bt + (size_t)(tN + r) * K + gs * 8;
    dA[p] = &lA[(p * 256 + w * 64) * 8];
    dB[p] = &lB[(p * 256 + w * 64) * 8];
  }

  fx4 acc[4][4];
#pragma unroll
  for (int m = 0; m < 4; ++m)
#pragma unroll
    for (int n = 0; n < 4; ++n) acc[m][n] = (fx4){0.f, 0.f, 0.f, 0.f};

  for (int kk = 0; kk < K; kk += 32) {
    __syncthreads();
#pragma unroll
    for (int p = 0; p < 2; ++p) {
      gload_lds16(sA[p] + kk, dA[p]);
      gload_lds16(sB[p] + kk, dB[p]);
    }
    __syncthreads();
    bf16x8 af[4], bfr[4];
#pragma unroll
    for (int m = 0; m < 4; ++m) {
      const int r = wr + m * 16 + lo;
      af[m] = *(const bf16x8*)&lA[r * 32 + ((hi ^ (r & 3)) << 3)];
    }
#pragma unroll
    for (int n = 0; n < 4; ++n) {
      const int r = wc + n * 16 + lo;
      bfr[n] = *(const bf16x8*)&lB[r * 32 + ((hi ^ (r & 3)) << 3)];
    }
#pragma unroll
    for (int m = 0; m < 4; ++m)
#pragma unroll
      for (int n = 0; n < 4; ++n) acc[m][n] = MFMA16(af[m], bfr[n], acc[m][n]);
  }

#pragma unroll
  for (int m = 0; m < 4; ++m) {
    const int rgb = tM + wr + m * 16 + hi * 4;
#pragma unroll
    for (int n = 0; n < 4; ++n) {
      const int cg = tN + wc + n * 16 + lo;
#pragma unroll
      for (int r = 0; r < 4; ++r) {
        const float v = acc[m][n][r];
        const int rg = rgb + r;
        if constexpr (MODE == 1) {
          float* o = (float*)outp;
          const size_t idx = (size_t)rg * 1024 + cg;
          o[idx] = aux[idx] + v;
        } else {
          float* o = (float*)outp;
          const size_t idx = (size_t)rg * 1024 + cg;
          o[idx] = o[idx] + v + aux[cg];
        }
      }
    }
  }
}

// ---------------- 256x256 pipelined bf16 GEMM (QKV / MLP1) ----------------
// 512 threads = 8 waves (2M x 4N); per-wave output 128x64; BK=64; LDS 128 KB.
// 2-tile-ahead staging with counted vmcnt(8); raw barriers; WAR barrier-separated.
// MODE 0: QKV scatter; MODE 2: g = bf16(gelu(acc + b1)) stride 4096.
template <int MODE>
__global__ __launch_bounds__(512, 1) void gemm256(
    const u16* __restrict__ A, const u16* __restrict__ Bt, int K,
    void* __restrict__ outp, const float* __restrict__ aux,
    u16* __restrict__ qd, u16* __restrict__ kd, u16* __restrict__ vd) {
  __shared__ u16 lds[2][2][256 * 64];  // [buf][0=A,1=B][row*64+col]
  const int tid = threadIdx.x;
  const int lane = tid & 63, w = tid >> 6;
  const int lo = lane & 15, hi = lane >> 4;
  const int wm = w >> 2, wn = w & 3;
  const int tM = blockIdx.y * 256, tN = blockIdx.x * 256;
  const int NT = K >> 6;

  // staging map: slot = ph*512+tid -> row=half*128+ph*64+(tid>>3), u=tid&7
  const int rb = tid >> 3;
  const int uc = ((tid & 7) ^ (rb & 7)) * 8;  // pre-swizzled source col (u16)

#define STGH(BUFI, XI, XPTR, TOFF, H, KK)                                        \
  do {                                                                           \
    _Pragma("unroll") for (int ph = 0; ph < 2; ++ph) {                           \
      const int rl = (H) * 128 + ph * 64 + rb;                                   \
      gload_lds16(XPTR + (size_t)((TOFF) + rl) * K + (KK) + uc,                  \
                  &lds[BUFI][XI][(H) * 8192 + ph * 4096 + tid * 8]);             \
    }                                                                            \
  } while (0)

  fx4 acc[8][4];
#pragma unroll
  for (int m = 0; m < 8; ++m)
#pragma unroll
    for (int n = 0; n < 4; ++n) acc[m][n] = (fx4){0.f, 0.f, 0.f, 0.f};

  // prologue: stage tiles 0 and 1
#pragma unroll
  for (int pt = 0; pt < 2; ++pt) {
    STGH(pt, 0, A, tM, 0, pt * 64);
    STGH(pt, 0, A, tM, 1, pt * 64);
    STGH(pt, 1, Bt, tN, 0, pt * 64);
    STGH(pt, 1, Bt, tN, 1, pt * 64);
  }

  for (int t = 0; t < NT; ++t) {
    const int bi = t & 1;
    const u16* bufA = &lds[bi][0][0];
    const u16* bufB = &lds[bi][1][0];
    if (t == NT - 1) {
      asm volatile("s_waitcnt vmcnt(0)" ::: "memory");
    } else {
      asm volatile("s_waitcnt vmcnt(8)" ::: "memory");  // tile t resident; t+1 in flight
    }
    __builtin_amdgcn_s_barrier();

    // cluster 1: all B frags (8) + A frags m0..3 (8)
    bf16x8 bfr[4][2], afr[4][2];
#pragma unroll
    for (int n = 0; n < 4; ++n)
#pragma unroll
      for (int ks = 0; ks < 2; ++ks) {
        const int R = wn * 64 + n * 16 + lo;
        bfr[n][ks] = *(const bf16x8*)&bufB[R * 64 + (((ks << 2) + hi) ^ (R & 7)) * 8];
      }
#pragma unroll
    for (int m = 0; m < 4; ++m)
#pragma unroll
      for (int ks = 0; ks < 2; ++ks) {
        const int R = wm * 128 + m * 16 + lo;
        afr[m][ks] = *(const bf16x8*)&bufA[R * 64 + (((ks << 2) + hi) ^ (R & 7)) * 8];
      }
    asm volatile("s_waitcnt lgkmcnt(0)" ::: "memory");
    __builtin_amdgcn_sched_barrier(0);
    __builtin_amdgcn_s_barrier();  // all waves' cluster-1 reads complete
    if (t + 2 < NT) {              // stage B(t+2) over the just-read B region
      STGH(bi, 1, Bt, tN, 0, (t + 2) * 64);
      STGH(bi, 1, Bt, tN, 1, (t + 2) * 64);
    }
    // cluster-2 reads (A m4..7) — disjoint from B stores; overlap with MFMA below
    bf16x8 afr2[4][2];
#pragma unroll
    for (int m = 0; m < 4; ++m)
#pragma unroll
      for (int ks = 0; ks < 2; ++ks) {
        const int R = wm * 128 + (m + 4) * 16 + lo;
        afr2[m][ks] = *(const bf16x8*)&bufA[R * 64 + (((ks << 2) + hi) ^ (R & 7)) * 8];
      }
    __builtin_amdgcn_s_setprio(1);
#pragma unroll
    for (int m = 0; m < 4; ++m)
#pragma unroll
      for (int n = 0; n < 4; ++n) {
        acc[m][n] = MFMA16(afr[m][0], bfr[n][0], acc[m][n]);
        acc[m][n] = MFMA16(afr[m][1], bfr[n][1], acc[m][n]);
      }
    __builtin_amdgcn_s_setprio(0);
    asm volatile("s_waitcnt lgkmcnt(0)" ::: "memory");
    __builtin_amdgcn_sched_barrier(0);
    __builtin_amdgcn_s_barrier();  // cluster-2 reads complete
    if (t + 2 < NT) {              // stage A(t+2)
      STGH(bi, 0, A, tM, 0, (t + 2) * 64);
      STGH(bi, 0, A, tM, 1, (t + 2) * 64);
    }
    __builtin_amdgcn_s_setprio(1);
#pragma unroll
    for (int m = 0; m < 4; ++m)
#pragma unroll
      for (int n = 0; n < 4; ++n) {
        acc[m + 4][n] = MFMA16(afr2[m][0], bfr[n][0], acc[m + 4][n]);
        acc[m + 4][n] = MFMA16(afr2[m][1], bfr[n][1], acc[m + 4][n]);
      }
    __builtin_amdgcn_s_setprio(0);
  }
#undef STGH

  // epilogue
#pragma unroll
  for (int m = 0; m < 8; ++m) {
    const int rgb = tM + wm * 128 + m * 16 + hi * 4;
#pragma unroll
    for (int n = 0; n < 4; ++n) {
      const int cg = tN + wn * 64 + n * 16 + lo;
#pragma unroll
      for (int r = 0; r < 4; ++r) {
        const float v = acc[m][n][r];
        const int rg = rgb + r;
        if constexpr (MODE == 0) {
          const int which = cg >> 10, c = cg & 1023;
          const int head = c >> 6, dhi = c & 63;
          const int b = rg >> 11, sidx = rg & 2047;
          const int bh = b * 16 + head;
          const u16 bv = f2bf(v);
          if (which == 0)      qd[((size_t)bh * 2048 + sidx) * 64 + dhi] = bv;
          else if (which == 1) kd[((size_t)bh * 2048 + sidx) * 64 + dhi] = bv;
          else                 vd[((size_t)bh * 64 + dhi) * 2048 + sidx] = bv;
        } else {
          const float xx = v + aux[cg];
          const float t2 = xx + 0.044715f * xx * xx * xx;
          const float e = __expf(1.5957691216057308f * t2);
          const float th = 1.f - 2.f / (e + 1.f);
          ((u16*)outp)[(size_t)rg * 4096 + cg] = f2bf(0.5f * xx * (1.f + th));
        }
      }
    }
  }
}

// ---------------- causal flash attention (unchanged from round 5) ----------------
__global__ __launch_bounds__(512) void attn_kernel(const u16* __restrict__ Q,
                                                   const u16* __restrict__ Kg,
                                                   const u16* __restrict__ Vt,
                                                   u16* __restrict__ ctx) {
  __shared__ u16 lK[2][64 * 64];
  __shared__ u16 lV[2][64 * 64];
  __shared__ u16 Plds[8][16 * 64];
  const int tid = threadIdx.x;
  const int w = tid >> 6, lane = tid & 63;
  const int lo = lane & 15, hi = lane >> 4;
  const int bh = blockIdx.x;
  const int j = blockIdx.y;
  const u16* Qb = Q + (size_t)bh * 2048 * 64;
  const u16* Kb = Kg + (size_t)bh * 2048 * 64;
  const u16* Vb = Vt + (size_t)bh * 64 * 2048;
  u16* Pw = Plds[w];
  const int nt0 = 2 * j + 2;

  const int rowS = tid >> 3;
  const int ugS = (tid & 7) ^ (rowS & 7);

#define STAGE(BUF, KB)                                                         \
  do {                                                                         \
    gload_lds16(Kb + (size_t)((KB) + rowS) * 64 + ugS * 8, &lK[BUF][tid * 8]); \
    gload_lds16(Vb + (size_t)rowS * 2048 + (KB) + ugS * 8, &lV[BUF][tid * 8]); \
  } while (0)

  const int b = bh >> 4, h = bh & 15;
  const float SCALE = 0.18033688011112042f;  // 0.125 * log2(e)

  int qt = j;
  int qw = qt * 128 + w * 16;

  bf16x8 qf[2];
#pragma unroll
  for (int kc = 0; kc < 2; ++kc)
    qf[kc] = *(const bf16x8*)&Qb[(size_t)(qw + lo) * 64 + kc * 32 + hi * 8];

  fx4 accO[4];
  float mrow[4], lrow[4];
#pragma unroll
  for (int t2 = 0; t2 < 4; ++t2) {
    accO[t2] = (fx4){0.f, 0.f, 0.f, 0.f};
    mrow[t2] = -1e30f;
    lrow[t2] = 0.f;
  }

  STAGE(0, 0);
  __syncthreads();

  int buf = 0;
  for (int t = 0; t < 34; ++t) {
    if (t + 1 < 34) {
      const int tn = t + 1;
      const int kbn = (tn < nt0 ? tn : tn - nt0) * 64;
      STAGE(buf ^ 1, kbn);
    }
    if (t == nt0) {
#pragma unroll
      for (int t2 = 0; t2 < 4; ++t2)
#pragma unroll
        for (int r = 0; r < 4; ++r) {
          const int rg = b * 2048 + qw + hi * 4 + r;
          const int cg = h * 64 + t2 * 16 + lo;
          ctx[(size_t)rg * 1024 + cg] = f2bf(accO[t2][r] / lrow[r]);
        }
      qt = 15 - j;
      qw = qt * 128 + w * 16;
#pragma unroll
      for (int kc = 0; kc < 2; ++kc)
        qf[kc] = *(const bf16x8*)&Qb[(size_t)(qw + lo) * 64 + kc * 32 + hi * 8];
#pragma unroll
      for (int t2 = 0; t2 < 4; ++t2) {
        accO[t2] = (fx4){0.f, 0.f, 0.f, 0.f};
        mrow[t2] = -1e30f;
        lrow[t2] = 0.f;
      }
    }
    const int kb = (t < nt0 ? t : t - nt0) * 64;
    if (kb <= qw + 15) {
      const u16* lKb = lK[buf];
      const u16* lVb = lV[buf];
      fx4 s[4];
#pragma unroll
      for (int tt = 0; tt < 4; ++tt) {
        const int r = tt * 16 + lo;
        const bf16x8 kf0 = *(const bf16x8*)&lKb[r * 64 + ((hi ^ (r & 7)) << 3)];
        const bf16x8 kf1 = *(const bf16x8*)&lKb[r * 64 + (((4 + hi) ^ (r & 7)) << 3)];
        fx4 z = (fx4){0.f, 0.f, 0.f, 0.f};
        z = MFMA16(qf[0], kf0, z);
        z = MFMA16(qf[1], kf1, z);
        s[tt] = z;
      }
      if (kb + 63 > qw) {
#pragma unroll
        for (int tt = 0; tt < 4; ++tt)
#pragma unroll
          for (int r = 0; r < 4; ++r) {
            const int key = kb + tt * 16 + lo;
            const int qr = qw + hi * 4 + r;
            s[tt][r] = (key > qr) ? -1e30f : s[tt][r] * SCALE;
          }
      } else {
#pragma unroll
        for (int tt = 0; tt < 4; ++tt)
#pragma unroll
          for (int r = 0; r < 4; ++r) s[tt][r] *= SCALE;
      }
      float mt[4];
#pragma unroll
      for (int r = 0; r < 4; ++r)
        mt[r] = fmaxf(fmaxf(s[0][r], s[1][r]), fmaxf(s[2][r], s[3][r]));
#pragma unroll
      for (int d = 8; d >= 1; d >>= 1)
#pragma unroll
        for (int r = 0; r < 4; ++r) mt[r] = fmaxf(mt[r], __shfl_xor(mt[r], d));
      bool ok = true;
#pragma unroll
      for (int r = 0; r < 4; ++r) ok = ok && (mt[r] <= mrow[r] + 8.f);
      if (!__all(ok)) {
#pragma unroll
        for (int r = 0; r < 4; ++r) {
          const float mn = fmaxf(mrow[r], mt[r]);
          const float fsc = exp2f(mrow[r] - mn);
          mrow[r] = mn;
          lrow[r] *= fsc;
#pragma unroll
          for (int t2 = 0; t2 < 4; ++t2) accO[t2][r] *= fsc;
        }
      }
      float la[4] = {0.f, 0.f, 0.f, 0.f};
#pragma unroll
      for (int tt = 0; tt < 4; ++tt)
#pragma unroll
        for (int r = 0; r < 4; ++r) {
          const float p = exp2f(s[tt][r] - mrow[r]);
          s[tt][r] = p;
          la[r] += p;
        }
#pragma unroll
      for (int d = 8; d >= 1; d >>= 1)
#pragma unroll
        for (int r = 0; r < 4; ++r) la[r] += __shfl_xor(la[r], d);
#pragma unroll
      for (int r = 0; r < 4; ++r) lrow[r] += la[r];
#pragma unroll
      for (int tt = 0; tt < 4; ++tt)
#pragma unroll
        for (int r = 0; r < 4; ++r) {
          const int row = hi * 4 + r;
          const int colB = (tt * 16 + lo) * 2;
          Pw[(row * 128 + (colB ^ ((row & 7) << 4))) >> 1] = f2bf(s[tt][r]);
        }
      asm volatile("s_waitcnt lgkmcnt(0)" ::: "memory");
      bf16x8 pf[2];
#pragma unroll
      for (int kc = 0; kc < 2; ++kc) {
        const int row = lo;
        const int colB = kc * 64 + hi * 16;
        pf[kc] = *(const bf16x8*)((const char*)Pw + row * 128 + (colB ^ ((row & 7) << 4)));
      }
#pragma unroll
      for (int t2 = 0; t2 < 4; ++t2) {
        const int r2 = t2 * 16 + lo;
        const bf16x8 vf0 = *(const bf16x8*)&lVb[r2 * 64 + ((hi ^ (r2 & 7)) << 3)];
        const bf16x8 vf1 = *(const bf16x8*)&lVb[r2 * 64 + (((4 + hi) ^ (r2 & 7)) << 3)];
        accO[t2] = MFMA16(pf[0], vf0, accO[t2]);
        accO[t2] = MFMA16(pf[1], vf1, accO[t2]);
      }
    }
    __syncthreads();
    buf ^= 1;
  }
#pragma unroll
  for (int t2 = 0; t2 < 4; ++t2)
#pragma unroll
    for (int r = 0; r < 4; ++r) {
      const int rg = b * 2048 + qw + hi * 4 + r;
      const int cg = h * 64 + t2 * 16 + lo;
      ctx[(size_t)rg * 1024 + cg] = f2bf(accO[t2][r] / lrow[r]);
    }
#undef STAGE
}

// ---------------- host ----------------
extern "C" void kernel_launch(void* const* d_in, const int* in_sizes, int n_in,
                              void* d_out, int out_size, void* d_ws, size_t ws_size,
                              hipStream_t stream) {
  const float* X    = (const float*)d_in[0];
  const float* Wq   = (const float*)d_in[1];
  const float* Wk   = (const float*)d_in[2];
  const float* Wv   = (const float*)d_in[3];
  const float* Wo   = (const float*)d_in[4];
  const float* W1   = (const float*)d_in[5];
  const float* b1   = (const float*)d_in[6];
  const float* W2   = (const float*)d_in[7];
  const float* b2   = (const float*)d_in[8];
  const float* ln1s = (const float*)d_in[9];
  const float* ln1b = (const float*)d_in[10];
  const float* ln2s = (const float*)d_in[11];
  const float* ln2b = (const float*)d_in[12];

  const size_t SZ_WQKVT = 3072UL * 1024;
  const size_t SZ_WOT   = 1024UL * 1024;
  const size_t SZ_W1T   = 4096UL * 1024;
  const size_t SZ_W2T   = 1024UL * 4096;
  const size_t SZ_H     = 8192UL * 1024;
  const size_t SZ_QKV   = 64UL * 2048 * 64;

  u16* WqkvT = (u16*)d_ws;
  u16* WoT   = WqkvT + SZ_WQKVT;
  u16* W1T   = WoT + SZ_WOT;
  u16* W2T   = W1T + SZ_W1T;
  u16* hbuf  = W2T + SZ_W2T;
  u16* qbuf  = hbuf + SZ_H;
  u16* kbuf  = qbuf + SZ_QKV;
  u16* vbuf  = kbuf + SZ_QKV;
  u16* gbuf  = vbuf + SZ_QKV;
  u16* ctx   = hbuf;  // reuse (h dead after QKV GEMM)
  u16* h2    = qbuf;  // reuse (q/k dead after attention)

  float* out = (float*)d_out;
  dim3 blk(256);

  // weights -> bf16 transposed
  tcvt<<<dim3(32, 32), blk, 0, stream>>>(Wq, WqkvT, 1024, 1024);
  tcvt<<<dim3(32, 32), blk, 0, stream>>>(Wk, WqkvT + 1024 * 1024, 1024, 1024);
  tcvt<<<dim3(32, 32), blk, 0, stream>>>(Wv, WqkvT + 2 * 1024 * 1024, 1024, 1024);
  tcvt<<<dim3(32, 32), blk, 0, stream>>>(Wo, WoT, 1024, 1024);
  tcvt<<<dim3(128, 32), blk, 0, stream>>>(W1, W1T, 1024, 4096);
  tcvt<<<dim3(32, 128), blk, 0, stream>>>(W2, W2T, 4096, 1024);

  // LN1
  ln_kernel<<<8192, blk, 0, stream>>>(X, ln1s, ln1b, hbuf);
  // QKV (256^2 pipelined)
  gemm256<0><<<dim3(12, 32), dim3(512), 0, stream>>>(hbuf, WqkvT, 1024,
                                                     nullptr, nullptr, qbuf, kbuf, vbuf);
  // attention
  attn_kernel<<<dim3(64, 8), dim3(512), 0, stream>>>(qbuf, kbuf, vbuf, ctx);
  // Wo + residual -> d_out (X1)
  gemm_bf16<1><<<dim3(8, 64), blk, 0, stream>>>(ctx, WoT, 8192, 1024, 1024,
                                                out, X, nullptr, nullptr, nullptr);
  // LN2
  ln_kernel<<<8192, blk, 0, stream>>>(out, ln2s, ln2b, h2);
  // MLP1: gelu(h2@W1 + b1) (256^2 pipelined)
  gemm256<2><<<dim3(16, 32), dim3(512), 0, stream>>>(h2, W1T, 1024,
                                                     gbuf, b1, nullptr, nullptr, nullptr);
  // MLP2: d_out = X1 + g@W2 + b2
  gemm_bf16<3><<<dim3(8, 64), blk, 0, stream>>>(gbuf, W2T, 8192, 1024, 4096,
                                                out, b2, nullptr, nullptr, nullptr);
}